// Round 7
// baseline (317.366 us; speedup 1.0000x reference)
//
#include <hip/hip_runtime.h>

typedef __bf16 bf16x8 __attribute__((ext_vector_type(8)));
typedef unsigned short u16x8 __attribute__((ext_vector_type(8)));
typedef unsigned short u16x4 __attribute__((ext_vector_type(4)));
typedef float f32x4 __attribute__((ext_vector_type(4)));
typedef float f32x16 __attribute__((ext_vector_type(16)));

#define B_    8
#define N_    1024
#define DIM_  1024
#define H_    8
#define HD_   128
#define SCALE_ 0.08838834764831845f

__device__ __forceinline__ unsigned short f2bf(float x) {
  unsigned int u = __float_as_uint(x);
  u += 0x7fffu + ((u >> 16) & 1u);           // RNE
  return (unsigned short)(u >> 16);
}
__device__ __forceinline__ float bf2f(unsigned short h) {
  return __uint_as_float(((unsigned int)h) << 16);
}
__device__ __forceinline__ f32x4 mfma16(u16x8 a, u16x8 b, f32x4 c) {
  return __builtin_amdgcn_mfma_f32_16x16x32_bf16(
      __builtin_bit_cast(bf16x8, a), __builtin_bit_cast(bf16x8, b), c, 0, 0, 0);
}
__device__ __forceinline__ f32x16 mfma32(u16x8 a, u16x8 b, f32x16 c) {
  return __builtin_amdgcn_mfma_f32_32x32x16_bf16(
      __builtin_bit_cast(bf16x8, a), __builtin_bit_cast(bf16x8, b), c, 0, 0, 0);
}
__device__ __forceinline__ void gl_lds16(const void* g, void* l) {
  __builtin_amdgcn_global_load_lds(
      (const __attribute__((address_space(1))) unsigned int*)g,
      (__attribute__((address_space(3))) unsigned int*)l, 16, 0, 0);
}
#define SBAR() do { asm volatile("" ::: "memory"); __builtin_amdgcn_s_barrier(); \
                    asm volatile("" ::: "memory"); } while (0)
#define LGKM0() do { asm volatile("s_waitcnt lgkmcnt(0)" ::: "memory"); \
                     __builtin_amdgcn_sched_barrier(0); } while (0)
#define VMC(n)  asm volatile("s_waitcnt vmcnt(" #n ")" ::: "memory")

// ---------------- workspace layout (bytes) ----------------
#define WS_KIMG  ((size_t)0)
#define WS_VIMG  ((size_t)32 << 20)
#define WS_WIMG  ((size_t)64 << 20)
#define WS_AOIMG ((size_t)68 << 20)

// ================= merged prep kernel =================
// sections: [0,1024) K, [1024,3072) V, [3072,3584) W
// K image per (bh): 32 tiles of (32 keys? no) -- unchanged from R6:
//   16 tiles of 64 keys, each = 2 d-half blocks of 16KB:
//   block byte = key*256 + hl*128 + ((dloc*2) ^ ((key&7)<<4))
// V image per (bh): 64 subtiles of 16 keys, 8KB each:
//   byte = hl*4096 + d*32 + ((key2*2) ^ ((d&1)<<4))
// W image: per (nt= n>>7, st= k>>5) 16KB tile:
//   byte = (n&127)*128 + ((hl*64 + (k&31)*2) ^ (((n&127)&7)<<4))
__global__ __launch_bounds__(256)
void prep_all(const float* __restrict__ gk, const float* __restrict__ gv,
              const float* __restrict__ gw, char* __restrict__ kimg,
              char* __restrict__ vimg, char* __restrict__ wimg) {
  const int blk = blockIdx.x;
  const int t = threadIdx.x;
  if (blk < 1024) {                          // ---- K ----
    const int bh = blk >> 4, it = blk & 15;
    const int bb = bh >> 3, hh = bh & 7;
    char* base = kimg + (size_t)bh * 524288 + it * 32768;
    const float* src = gk + ((size_t)bb * N_ + it * 64) * DIM_ + hh * HD_;
    #pragma unroll
    for (int c = 0; c < 8; ++c) {
      const int idx = t + 256 * c;
      const int key = idx >> 5, dq = (idx & 31) * 4;
      f32x4 f = *(const f32x4*)(src + (size_t)key * DIM_ + dq);
      u16x4 h, g;
      #pragma unroll
      for (int j = 0; j < 4; ++j) {
        unsigned short hv = f2bf(f[j]);
        h[j] = hv;
        g[j] = f2bf(f[j] - bf2f(hv));
      }
      const int dh = dq >> 6, dloc = dq & 63;
      const int off = (dloc * 2) ^ ((key & 7) << 4);
      char* dst = base + dh * 16384 + key * 256;
      *(u16x4*)(dst + off) = h;
      *(u16x4*)(dst + 128 + off) = g;
    }
  } else if (blk < 3072) {                   // ---- V ----
    __shared__ float tile[32][132];
    const int b2 = blk - 1024;               // bh*32 + kt   (32-key pair)
    const int bh = b2 >> 5, kt = b2 & 31;
    const int bb = bh >> 3, hh = bh & 7;
    const float* src = gv + ((size_t)bb * N_ + kt * 32) * DIM_ + hh * HD_;
    #pragma unroll
    for (int c = 0; c < 4; ++c) {
      const int idx = t + 256 * c;
      const int key = idx >> 5, dq = (idx & 31) * 4;
      *(f32x4*)&tile[key][dq] = *(const f32x4*)(src + (size_t)key * DIM_ + dq);
    }
    __syncthreads();
    char* base = vimg + (size_t)bh * 524288 + kt * 16384;  // 2 subtiles
    #pragma unroll
    for (int c = 0; c < 2; ++c) {
      const int idx = t + 256 * c;           // 0..511
      const int d = idx >> 2, koct = idx & 3;
      const int sb = koct >> 1, k8 = (koct & 1) * 8;
      u16x8 h, g;
      #pragma unroll
      for (int j = 0; j < 8; ++j) {
        float x = tile[sb * 16 + k8 + j][d];
        unsigned short hv = f2bf(x);
        h[j] = hv;
        g[j] = f2bf(x - bf2f(hv));
      }
      const int off = d * 32 + ((k8 * 2) ^ ((d & 1) << 4));
      char* dst = base + sb * 8192;
      *(u16x8*)(dst + off) = h;
      *(u16x8*)(dst + 4096 + off) = g;
    }
  } else {                                   // ---- W ----
    const int idx = (blk - 3072) * 256 + t;  // 0..131071
    const int n = idx >> 7, k8 = idx & 127;
    const int k0 = k8 * 8;
    const float* s = gw + (size_t)n * DIM_ + k0;
    f32x4 f0 = *(const f32x4*)s;
    f32x4 f1 = *(const f32x4*)(s + 4);
    u16x8 h, g;
    #pragma unroll
    for (int j = 0; j < 8; ++j) {
      float x = j < 4 ? f0[j] : f1[j - 4];
      unsigned short hv = f2bf(x);
      h[j] = hv;
      g[j] = f2bf(x - bf2f(hv));
    }
    const int T = (n >> 7) * 32 + (k0 >> 5);
    const int rl = n & 127, kl = k0 & 31;
    char* base = wimg + (size_t)T * 16384 + rl * 128;
    const int swz = (rl & 7) << 4;
    *(u16x8*)(base + ((kl * 2) ^ swz)) = h;
    *(u16x8*)(base + ((64 + kl * 2) ^ swz)) = g;
  }
}

// ================= attention kernel (1024 threads, 16 waves) =================
struct K1Smem {
  unsigned short p[64 * 1024];            // 131072 B: p[row][key], byte ^ ((row&7)<<4)
  union {
    char kb[2][16384];                    // QK: K half-d tiles (dbuf)
    char vb[4][8192];                     // PV: V 16-key subtiles (4-buf)
    char comb[8][4096];                   // epilogue: O-combine
    struct { char pad[16384]; float partial[4][64]; float rinv[64]; } pp;
  } u;
};

__global__ __launch_bounds__(1024, 4)
void attn_kernel(const float* __restrict__ gq, const char* __restrict__ kimg,
                 const char* __restrict__ vimg, float* __restrict__ gattn,
                 char* __restrict__ aoimg) {
  __shared__ K1Smem sm;
  const int bid = blockIdx.x;
  const int xcd = bid & 7, slot = bid >> 3;
  const int bh = xcd + 8 * (slot >> 4);
  const int qt = slot & 15;
  const int bb = bh >> 3, hh = bh & 7;

  const int tid = threadIdx.x;
  const int wid = tid >> 6, lane = tid & 63;
  const int rg = wid >> 2;                   // QK: 0..3 row group (16 rows)
  const int kg = wid & 3;                    // QK key group / PV d group
  const int l15 = lane & 15, l4 = lane >> 4;
  // PV wave roles: rg2 (32-row half) x kg4 (32-d) x kh2 (even/odd subtile)
  const int prg = wid >> 3;                  // 0..1
  const int pkg = kg;                        // 0..3
  const int pkh = (wid >> 2) & 1;            // 0..1
  const int l31 = lane & 31, l5 = lane >> 5;

  const char* kimg_bh = kimg + (size_t)bh * 524288;
  const char* vimg_bh = vimg + (size_t)bh * 524288;

  auto issueK = [&](int s) {                 // 16KB tile s -> kb[s&1]
    const char* src = kimg_bh + s * 16384 + wid * 1024 + lane * 16;
    gl_lds16(src, sm.u.kb[s & 1] + wid * 1024);
  };
  auto issueVpair = [&](int pairbase) {      // subtiles pairbase + (wid>>3)
    const int sb = pairbase + (wid >> 3);
    const char* src = vimg_bh + (size_t)sb * 8192 + (wid & 7) * 1024 + lane * 16;
    gl_lds16(src, sm.u.vb[sb & 3] + (wid & 7) * 1024);
  };

  issueK(0);

  // ---------------- Q fragments ----------------
  u16x8 qhi[4], qlo[4];
  {
    const int qrow = qt * 64 + rg * 16 + l15;
    const float* qp = gq + ((size_t)bb * N_ + qrow) * DIM_ + hh * HD_;
    #pragma unroll
    for (int t = 0; t < 4; ++t) {
      const int d0 = t * 32 + l4 * 8;
      f32x4 f0 = *(const f32x4*)(qp + d0);
      f32x4 f1 = *(const f32x4*)(qp + d0 + 4);
      #pragma unroll
      for (int j = 0; j < 8; ++j) {
        float x = (j < 4 ? f0[j] : f1[j - 4]) * SCALE_;
        unsigned short hi = f2bf(x);
        qhi[t][j] = hi;
        qlo[t][j] = f2bf(x - bf2f(hi));
      }
    }
  }

  issueK(1);
  VMC(1);
  SBAR();

  // ---------------- Phase 1: S = K Q^T ----------------
  float lsum = 0.f;
  const int key16 = kg * 16 + l15;
  const int kswz = (key16 & 7) << 4;
  const char* krow0 = sm.u.kb[0] + key16 * 256;
  const char* krow1 = sm.u.kb[1] + key16 * 256;
  const int prow_i = rg * 16 + l15;
  char* const prow = (char*)sm.p + prow_i * 2048;
  const int pswz = (prow_i & 7) << 4;

  f32x4 a0, a1, a2;
  #pragma unroll 2
  for (int s = 0; s < 32; ++s) {
    const int dh = s & 1;
    if (s >= 1 && s < 31) issueK(s + 1);
    else if (s == 31) issueVpair(0);         // V subtiles 0,1 -> vb[0],vb[1]
    const char* krow = dh ? krow1 : krow0;
    u16x8 khi[2], klo[2];
    #pragma unroll
    for (int tl = 0; tl < 2; ++tl) {
      const int off = (tl * 64 + l4 * 16) ^ kswz;
      khi[tl] = *(const u16x8*)(krow + off);
      klo[tl] = *(const u16x8*)(krow + 128 + off);
    }
    if (dh == 0) {
      a0 = f32x4{0.f, 0.f, 0.f, 0.f};
      a1 = f32x4{0.f, 0.f, 0.f, 0.f};
      a2 = f32x4{0.f, 0.f, 0.f, 0.f};
    }
    __builtin_amdgcn_s_setprio(1);
    #pragma unroll
    for (int tl = 0; tl < 2; ++tl) {
      const int t = dh * 2 + tl;
      a0 = mfma16(khi[tl], qhi[t], a0);
      a1 = mfma16(klo[tl], qhi[t], a1);
      a2 = mfma16(khi[tl], qlo[t], a2);
    }
    __builtin_amdgcn_s_setprio(0);
    if (dh == 1) {
      const int keyb = ((s >> 1) * 64 + kg * 16 + l4 * 4) * 2;
      u16x4 pk;
      float ls = 0.f;
      #pragma unroll
      for (int r = 0; r < 4; ++r) {
        float sv = (a0[r] + a1[r]) + a2[r];
        sv = fminf(sv, 60.0f);
        float p = __expf(sv);
        ls += p;
        pk[r] = f2bf(p);
      }
      lsum += ls;
      *(u16x4*)(prow + (keyb ^ pswz)) = pk;
    }
    if (s < 31) { VMC(0); }
    else       { VMC(2); }                   // keep V pair in flight
    SBAR();
  }

  // ---------------- rowsums -> partial -> rinv ----------------
  {
    float s0 = lsum;
    s0 += __shfl_xor(s0, 16);
    s0 += __shfl_xor(s0, 32);
    if (lane < 16) sm.u.pp.partial[kg][rg * 16 + lane] = s0;
  }
  LGKM0();
  SBAR();
  if (tid < 64) {
    float t4 = sm.u.pp.partial[0][tid] + sm.u.pp.partial[1][tid] +
               sm.u.pp.partial[2][tid] + sm.u.pp.partial[3][tid];
    sm.u.pp.rinv[tid] = 1.0f / t4;
  }
  LGKM0();
  SBAR();
  // preload all rinv values needed later (before V staging clobbers the table)
  const float rvw = sm.u.pp.rinv[prg * 32 + l31];     // for attn writes (A-frag row)
  float rv16[16];
  if (pkh == 0) {
    #pragma unroll
    for (int r = 0; r < 16; ++r) {
      const int rowreg = (r & 3) + 8 * (r >> 2) + 4 * l5;
      rv16[r] = sm.u.pp.rinv[prg * 32 + rowreg];
    }
  }
  LGKM0();                                   // all rinv reads done
  VMC(0);                                    // V subtiles 0,1 landed
  SBAR();

  // ---------------- Phase 2: PV (32x32x16, kh-split subtiles) ----------------
  f32x16 acc = {};
  const char* pArow = (const char*)sm.p + (prg * 32 + l31) * 2048;
  const int paswz = ((prg * 32 + l31) & 7) << 4;
  float* arow = gattn + ((size_t)bh * N_ + qt * 64 + prg * 32 + l31) * N_;

  #pragma unroll 1
  for (int t = 0; t < 32; ++t) {
    if (t < 31) issueVpair(2 * (t + 1));     // subtiles 2t+2, 2t+3
    const int s = 2 * t + pkh;               // this wave's subtile
    const char* vbase = sm.u.vb[s & 3];
    const int d = pkg * 32 + l31;
    const int voff = d * 32 + ((l5 * 16) ^ ((d & 1) << 4));
    u16x8 vh = *(const u16x8*)(vbase + voff);
    u16x8 vl = *(const u16x8*)(vbase + 4096 + voff);
    u16x8 pa = *(const u16x8*)(pArow + ((s * 32 + l5 * 16) ^ paswz));
    __builtin_amdgcn_s_setprio(1);
    acc = mfma32(pa, vh, acc);
    acc = mfma32(pa, vl, acc);
    __builtin_amdgcn_s_setprio(0);
    const bool wr = ((t & 3) == pkg);
    if (wr) {                                // spread attn writes: 4 waves/step
      f32x4 o0, o1;
      o0[0] = bf2f(pa[0]) * rvw; o0[1] = bf2f(pa[1]) * rvw;
      o0[2] = bf2f(pa[2]) * rvw; o0[3] = bf2f(pa[3]) * rvw;
      o1[0] = bf2f(pa[4]) * rvw; o1[1] = bf2f(pa[5]) * rvw;
      o1[2] = bf2f(pa[6]) * rvw; o1[3] = bf2f(pa[7]) * rvw;
      float* dst = arow + s * 16 + l5 * 8;
      __builtin_nontemporal_store(o0, (f32x4*)dst);
      __builtin_nontemporal_store(o1, (f32x4*)(dst + 4));
    }
    LGKM0();                                 // vb/p reads drained
    if (t < 31) {
      if (wr) { VMC(2); }                    // leave the 2 stores in flight
      else    { VMC(0); }
    }
    SBAR();
  }

  // ---------------- O-combine across kh pairs ----------------
  {
    char* cbase = sm.u.comb[prg * 4 + pkg] + lane * 64;
    if (pkh == 1) {
      #pragma unroll
      for (int q = 0; q < 4; ++q) {
        f32x4 v = {acc[q * 4], acc[q * 4 + 1], acc[q * 4 + 2], acc[q * 4 + 3]};
        *(f32x4*)(cbase + q * 16) = v;
      }
    }
    LGKM0();
    SBAR();
    if (pkh == 0) {
      #pragma unroll
      for (int q = 0; q < 4; ++q) {
        f32x4 v = *(const f32x4*)(cbase + q * 16);
        acc[q * 4] += v[0]; acc[q * 4 + 1] += v[1];
        acc[q * 4 + 2] += v[2]; acc[q * 4 + 3] += v[3];
      }
      // epilogue: ao -> proj-image layout (bf16 hi/lo)
      const int col5 = hh * 4 + pkg;         // (col>>5)
      const int mt = bb * 8 + (qt >> 1);
      char* Tbase = aoimg + ((size_t)(mt * 32 + col5)) * 16384;
      const int klb = (l31) * 2;             // kl*2
      #pragma unroll
      for (int r = 0; r < 16; ++r) {
        const int rowreg = (r & 3) + 8 * (r >> 2) + 4 * l5;
        const int rl = (qt & 1) * 64 + prg * 32 + rowreg;
        const int swz = (rl & 7) << 4;
        float val = acc[r] * rv16[r];
        unsigned short hv = f2bf(val);
        unsigned short lv = f2bf(val - bf2f(hv));
        char* rp = Tbase + rl * 128;
        __builtin_nontemporal_store(hv, (unsigned short*)(rp + (klb ^ swz)));
        __builtin_nontemporal_store(lv, (unsigned short*)(rp + ((64 + klb) ^ swz)));
      }
    }
  }
}

// ================= K2: out = ao @ W^T + b (128x128 tiles, 512 blocks) =================
struct K2Smem {
  char A[2][16384];
  char Bm[2][16384];
};

__global__ __launch_bounds__(512, 2)
void proj_kernel(const char* __restrict__ aoimg, const char* __restrict__ wimg,
                 const float* __restrict__ gbias, float* __restrict__ gout) {
  __shared__ K2Smem sm;
  // 512 blocks = 64 mt x 8 nt; nt = XCD (W slice L2-resident)
  const int nt = blockIdx.x & 7;
  const int mt = blockIdx.x >> 3;
  const int tid = threadIdx.x;
  const int wid = tid >> 6, lane = tid & 63;
  const int wr = wid >> 2, wc = wid & 3;     // wave: 64 rows x 32 cols
  const int l15 = lane & 15, l4 = lane >> 4;

  auto issue = [&](int s) {
    const char* sa = aoimg + ((size_t)(mt * 32 + s)) * 16384 + tid * 16;
    gl_lds16(sa, sm.A[s & 1] + (tid >> 6) * 1024);
    gl_lds16(sa + 8192, sm.A[s & 1] + 8192 + (tid >> 6) * 1024);
    const char* sb = wimg + ((size_t)(nt * 32 + s)) * 16384 + tid * 16;
    gl_lds16(sb, sm.Bm[s & 1] + (tid >> 6) * 1024);
    gl_lds16(sb + 8192, sm.Bm[s & 1] + 8192 + (tid >> 6) * 1024);
  };

  f32x4 acc[4][2];
  #pragma unroll
  for (int i = 0; i < 4; ++i)
    #pragma unroll
    for (int j = 0; j < 2; ++j) acc[i][j] = f32x4{0.f, 0.f, 0.f, 0.f};

  issue(0);
  VMC(0);
  SBAR();
  #pragma unroll 1
  for (int s = 0; s < 32; ++s) {
    if (s < 31) issue(s + 1);
    const char* Ab = sm.A[s & 1];
    const char* Bb = sm.Bm[s & 1];
    u16x8 ah[4], al[4], bh[2], bl[2];
    #pragma unroll
    for (int rt = 0; rt < 4; ++rt) {
      const int rl = wr * 64 + rt * 16 + l15;
      const char* rp = Ab + rl * 128;
      const int swz = (rl & 7) << 4;
      ah[rt] = *(const u16x8*)(rp + ((l4 * 16) ^ swz));
      al[rt] = *(const u16x8*)(rp + ((64 + l4 * 16) ^ swz));
    }
    #pragma unroll
    for (int ct = 0; ct < 2; ++ct) {
      const int cl = wc * 32 + ct * 16 + l15;
      const char* rp = Bb + cl * 128;
      const int swz = (cl & 7) << 4;
      bh[ct] = *(const u16x8*)(rp + ((l4 * 16) ^ swz));
      bl[ct] = *(const u16x8*)(rp + ((64 + l4 * 16) ^ swz));
    }
    __builtin_amdgcn_s_setprio(1);
    #pragma unroll
    for (int rt = 0; rt < 4; ++rt)
      #pragma unroll
      for (int ct = 0; ct < 2; ++ct)
        acc[rt][ct] = mfma16(ah[rt], bh[ct], acc[rt][ct]);
    #pragma unroll
    for (int rt = 0; rt < 4; ++rt)
      #pragma unroll
      for (int ct = 0; ct < 2; ++ct)
        acc[rt][ct] = mfma16(ah[rt], bl[ct], acc[rt][ct]);
    #pragma unroll
    for (int rt = 0; rt < 4; ++rt)
      #pragma unroll
      for (int ct = 0; ct < 2; ++ct)
        acc[rt][ct] = mfma16(al[rt], bh[ct], acc[rt][ct]);
    __builtin_amdgcn_s_setprio(0);
    LGKM0();
    if (s < 31) VMC(0);
    SBAR();
  }

  #pragma unroll
  for (int ct = 0; ct < 2; ++ct) {
    const int col = nt * 128 + wc * 32 + ct * 16 + l15;
    const float bv = gbias[col];
    #pragma unroll
    for (int rt = 0; rt < 4; ++rt) {
      float* dst = gout + (size_t)(mt * 128 + wr * 64 + rt * 16 + l4 * 4) * DIM_ + col;
      #pragma unroll
      for (int r = 0; r < 4; ++r)
        dst[(size_t)r * DIM_] = acc[rt][ct][r] + bv;
    }
  }
}

extern "C" void kernel_launch(void* const* d_in, const int* in_sizes, int n_in,
                              void* d_out, int out_size, void* d_ws, size_t ws_size,
                              hipStream_t stream) {
  const float* q    = (const float*)d_in[0];
  const float* k    = (const float*)d_in[1];
  const float* v    = (const float*)d_in[2];
  const float* W    = (const float*)d_in[3];
  const float* bias = (const float*)d_in[4];
  float* out  = (float*)d_out;
  float* attn = out + (size_t)B_ * N_ * DIM_;      // outputs: [out | attn]

  char* ws = (char*)d_ws;                          // needs 100 MB
  char* kimg  = ws + WS_KIMG;
  char* vimg  = ws + WS_VIMG;
  char* wimg  = ws + WS_WIMG;
  char* aoimg = ws + WS_AOIMG;

  prep_all<<<3584, 256, 0, stream>>>(k, v, W, kimg, vimg, wimg);
  attn_kernel<<<B_ * H_ * (N_ / 64), 1024, 0, stream>>>(q, kimg, vimg, attn, aoimg);
  proj_kernel<<<512, 512, 0, stream>>>(aoimg, wimg, bias, out);
}

// Round 8
// 243.423 us; speedup vs baseline: 1.3038x; 1.3038x over previous
//
#include <hip/hip_runtime.h>

typedef __bf16 bf16x8 __attribute__((ext_vector_type(8)));
typedef unsigned short u16x8 __attribute__((ext_vector_type(8)));
typedef unsigned short u16x4 __attribute__((ext_vector_type(4)));
typedef float f32x4 __attribute__((ext_vector_type(4)));
typedef float f32x16 __attribute__((ext_vector_type(16)));

#define B_    8
#define N_    1024
#define DIM_  1024
#define H_    8
#define HD_   128
#define SCALE_ 0.08838834764831845f

__device__ __forceinline__ unsigned short f2bf(float x) {
  unsigned int u = __float_as_uint(x);
  u += 0x7fffu + ((u >> 16) & 1u);           // RNE
  return (unsigned short)(u >> 16);
}
__device__ __forceinline__ float bf2f(unsigned short h) {
  return __uint_as_float(((unsigned int)h) << 16);
}
__device__ __forceinline__ f32x4 mfma16(u16x8 a, u16x8 b, f32x4 c) {
  return __builtin_amdgcn_mfma_f32_16x16x32_bf16(
      __builtin_bit_cast(bf16x8, a), __builtin_bit_cast(bf16x8, b), c, 0, 0, 0);
}
__device__ __forceinline__ f32x16 mfma32(u16x8 a, u16x8 b, f32x16 c) {
  return __builtin_amdgcn_mfma_f32_32x32x16_bf16(
      __builtin_bit_cast(bf16x8, a), __builtin_bit_cast(bf16x8, b), c, 0, 0, 0);
}
__device__ __forceinline__ void gl_lds16(const void* g, void* l) {
  __builtin_amdgcn_global_load_lds(
      (const __attribute__((address_space(1))) unsigned int*)g,
      (__attribute__((address_space(3))) unsigned int*)l, 16, 0, 0);
}
#define SBAR() do { asm volatile("" ::: "memory"); __builtin_amdgcn_s_barrier(); \
                    asm volatile("" ::: "memory"); } while (0)
#define LGKM0() do { asm volatile("s_waitcnt lgkmcnt(0)" ::: "memory"); \
                     __builtin_amdgcn_sched_barrier(0); } while (0)
#define VMC(n)  asm volatile("s_waitcnt vmcnt(" #n ")" ::: "memory")

// ---------------- workspace layout (bytes) ----------------
#define WS_KIMG  ((size_t)0)
#define WS_VIMG  ((size_t)32 << 20)
#define WS_WIMG  ((size_t)64 << 20)
#define WS_AOIMG ((size_t)68 << 20)

// ================= merged prep kernel =================
// sections: [0,1024) K, [1024,3072) V, [3072,3584) W
// K image per (bh): 16 tiles of 64 keys, each = 2 d-half blocks of 16KB:
//   block byte = key*256 + hl*128 + ((dloc*2) ^ ((key&7)<<4))
// V image per (bh): 32 tiles of 32 keys, 16KB = [hi 8KB | lo 8KB]:
//   plane byte = (d*64 + key*2) ^ ((d&7)<<4)   (d-major)
// W image: per (n>>7, k>>5) 16KB tile: byte = (n&127)*128 + ((hl*64+(k&31)*2) ^ (((n&127)&7)<<4))
__global__ __launch_bounds__(256)
void prep_all(const float* __restrict__ gk, const float* __restrict__ gv,
              const float* __restrict__ gw, char* __restrict__ kimg,
              char* __restrict__ vimg, char* __restrict__ wimg) {
  const int blk = blockIdx.x;
  const int t = threadIdx.x;
  if (blk < 1024) {                          // ---- K ----
    const int bh = blk >> 4, it = blk & 15;
    const int bb = bh >> 3, hh = bh & 7;
    char* base = kimg + (size_t)bh * 524288 + it * 32768;
    const float* src = gk + ((size_t)bb * N_ + it * 64) * DIM_ + hh * HD_;
    #pragma unroll
    for (int c = 0; c < 8; ++c) {
      const int idx = t + 256 * c;
      const int key = idx >> 5, dq = (idx & 31) * 4;
      f32x4 f = *(const f32x4*)(src + (size_t)key * DIM_ + dq);
      u16x4 h, g;
      #pragma unroll
      for (int j = 0; j < 4; ++j) {
        unsigned short hv = f2bf(f[j]);
        h[j] = hv;
        g[j] = f2bf(f[j] - bf2f(hv));
      }
      const int dh = dq >> 6, dloc = dq & 63;
      const int off = (dloc * 2) ^ ((key & 7) << 4);
      char* dst = base + dh * 16384 + key * 256;
      *(u16x4*)(dst + off) = h;
      *(u16x4*)(dst + 128 + off) = g;
    }
  } else if (blk < 3072) {                   // ---- V ----
    __shared__ float tile[32][132];
    const int b2 = blk - 1024;               // bh*32 + kt
    const int bh = b2 >> 5, kt = b2 & 31;
    const int bb = bh >> 3, hh = bh & 7;
    const float* src = gv + ((size_t)bb * N_ + kt * 32) * DIM_ + hh * HD_;
    #pragma unroll
    for (int c = 0; c < 4; ++c) {
      const int idx = t + 256 * c;
      const int key = idx >> 5, dq = (idx & 31) * 4;
      *(f32x4*)&tile[key][dq] = *(const f32x4*)(src + (size_t)key * DIM_ + dq);
    }
    __syncthreads();
    char* base = vimg + (size_t)bh * 524288 + kt * 16384;
    #pragma unroll
    for (int c = 0; c < 2; ++c) {
      const int oc = t + 256 * c;            // 0..511
      const int d = oc >> 2, kc = oc & 3;
      u16x8 h, g;
      #pragma unroll
      for (int j = 0; j < 8; ++j) {
        float x = tile[kc * 8 + j][d];
        unsigned short hv = f2bf(x);
        h[j] = hv;
        g[j] = f2bf(x - bf2f(hv));
      }
      const int off = (d * 64 + kc * 16) ^ ((d & 7) << 4);
      *(u16x8*)(base + off) = h;
      *(u16x8*)(base + 8192 + off) = g;
    }
  } else {                                   // ---- W ----
    const int idx = (blk - 3072) * 256 + t;  // 0..131071
    const int n = idx >> 7, k0 = (idx & 127) * 8;
    const float* s = gw + (size_t)n * DIM_ + k0;
    f32x4 f0 = *(const f32x4*)s;
    f32x4 f1 = *(const f32x4*)(s + 4);
    u16x8 h, g;
    #pragma unroll
    for (int j = 0; j < 8; ++j) {
      float x = j < 4 ? f0[j] : f1[j - 4];
      unsigned short hv = f2bf(x);
      h[j] = hv;
      g[j] = f2bf(x - bf2f(hv));
    }
    const int T = (n >> 7) * 32 + (k0 >> 5);
    const int rl = n & 127, kl = k0 & 31;
    char* base = wimg + (size_t)T * 16384 + rl * 128;
    const int swz = (rl & 7) << 4;
    *(u16x8*)(base + ((kl * 2) ^ swz)) = h;
    *(u16x8*)(base + ((64 + kl * 2) ^ swz)) = g;
  }
}

// ================= attention kernel (1024 threads, 16 waves) =================
struct K1Smem {
  unsigned short p[64 * 1024];            // 131072 B: p[row][key], byte = row*2048 + (col2 ^ ((row&7)<<4))
  union {
    char kb[2][16384];                    // QK: K half-d tiles (dbuf)
    char vt[2][16384];                    // PV: V 32-key tiles (dbuf)
    char comb[8][4096];                   // epilogue: O-combine
    struct { char pad[16384]; float partial[4][64]; float rinv[64]; } pp;
  } u;
};

__global__ __launch_bounds__(1024, 4)
void attn_kernel(const float* __restrict__ gq, const char* __restrict__ kimg,
                 const char* __restrict__ vimg, float* __restrict__ gattn,
                 char* __restrict__ aoimg) {
  __shared__ K1Smem sm;
  const int bid = blockIdx.x;
  const int xcd = bid & 7, slot = bid >> 3;
  const int bh = xcd + 8 * (slot >> 4);
  const int qt = slot & 15;
  const int bb = bh >> 3, hh = bh & 7;

  const int tid = threadIdx.x;
  const int wid = tid >> 6, lane = tid & 63;
  const int rg = wid >> 2;                   // QK: 0..3 row group (16 rows)
  const int kg = wid & 3;                    // QK: key group
  const int l15 = lane & 15, l4 = lane >> 4;
  // PV roles: prg = 32-row half, pkg = 32-d group, pkh = 16-key half
  const int prg = wid >> 3;                  // 0..1
  const int pkg = wid & 3;                   // 0..3
  const int pkh = (wid >> 2) & 1;            // 0..1
  const int l31 = lane & 31, l5 = lane >> 5;

  const char* kimg_bh = kimg + (size_t)bh * 524288;
  const char* vimg_bh = vimg + (size_t)bh * 524288;

  auto issueK = [&](int s) {                 // 16KB tile s -> kb[s&1]
    const char* src = kimg_bh + s * 16384 + wid * 1024 + lane * 16;
    gl_lds16(src, sm.u.kb[s & 1] + wid * 1024);
  };
  auto issueV = [&](int kt) {                // 16KB tile kt -> vt[kt&1]
    const char* src = vimg_bh + kt * 16384 + wid * 1024 + lane * 16;
    gl_lds16(src, sm.u.vt[kt & 1] + wid * 1024);
  };

  issueK(0);

  // ---------------- Q fragments (16 rows/wave, pre-scaled, hi/lo split) ----------------
  u16x8 qhi[4], qlo[4];
  {
    const int qrow = qt * 64 + rg * 16 + l15;
    const float* qp = gq + ((size_t)bb * N_ + qrow) * DIM_ + hh * HD_;
    #pragma unroll
    for (int t = 0; t < 4; ++t) {
      const int d0 = t * 32 + l4 * 8;
      f32x4 f0 = *(const f32x4*)(qp + d0);
      f32x4 f1 = *(const f32x4*)(qp + d0 + 4);
      #pragma unroll
      for (int j = 0; j < 8; ++j) {
        float x = (j < 4 ? f0[j] : f1[j - 4]) * SCALE_;
        unsigned short hi = f2bf(x);
        qhi[t][j] = hi;
        qlo[t][j] = f2bf(x - bf2f(hi));
      }
    }
  }

  issueK(1);
  VMC(1);                                    // K0 landed (K1 in flight)
  SBAR();

  // ---------------- Phase 1: S = K Q^T (swapped: lane holds 4 keys x 1 qrow) ----------------
  float lsum = 0.f;
  const int key16 = kg * 16 + l15;
  const int kswz = (key16 & 7) << 4;
  const char* krow0 = sm.u.kb[0] + key16 * 256;
  const char* krow1 = sm.u.kb[1] + key16 * 256;
  const int prow_i = rg * 16 + l15;
  char* const prow = (char*)sm.p + prow_i * 2048;
  const int pswz = (prow_i & 7) << 4;

  f32x4 a0, a1, a2;
  #pragma unroll 2
  for (int s = 0; s < 32; ++s) {
    const int dh = s & 1;
    if (s >= 1 && s < 31) issueK(s + 1);
    else if (s == 31) issueV(0);             // vt[0] aliases kb[0] (dead since s==30)
    const char* krow = dh ? krow1 : krow0;
    u16x8 khi[2], klo[2];
    #pragma unroll
    for (int tl = 0; tl < 2; ++tl) {
      const int off = (tl * 64 + l4 * 16) ^ kswz;
      khi[tl] = *(const u16x8*)(krow + off);
      klo[tl] = *(const u16x8*)(krow + 128 + off);
    }
    if (dh == 0) {
      a0 = f32x4{0.f, 0.f, 0.f, 0.f};
      a1 = f32x4{0.f, 0.f, 0.f, 0.f};
      a2 = f32x4{0.f, 0.f, 0.f, 0.f};
    }
    __builtin_amdgcn_s_setprio(1);
    #pragma unroll
    for (int tl = 0; tl < 2; ++tl) {
      const int t = dh * 2 + tl;
      a0 = mfma16(khi[tl], qhi[t], a0);
      a1 = mfma16(klo[tl], qhi[t], a1);
      a2 = mfma16(khi[tl], qlo[t], a2);
    }
    __builtin_amdgcn_s_setprio(0);
    if (dh == 1) {
      const int keyb = ((s >> 1) * 64 + kg * 16 + l4 * 4) * 2;
      u16x4 pk;
      float ls = 0.f;
      #pragma unroll
      for (int r = 0; r < 4; ++r) {
        float sv = (a0[r] + a1[r]) + a2[r];
        sv = fminf(sv, 60.0f);
        float p = __expf(sv);
        ls += p;
        pk[r] = f2bf(p);
      }
      lsum += ls;
      *(u16x4*)(prow + (keyb ^ pswz)) = pk;
    }
    if (s < 31) { VMC(0); }
    else       { VMC(2); }                   // keep V0 in flight
    SBAR();
  }

  // ---------------- rowsums -> partial -> rinv ----------------
  {
    float s0 = lsum;
    s0 += __shfl_xor(s0, 16);
    s0 += __shfl_xor(s0, 32);
    if (lane < 16) sm.u.pp.partial[kg][rg * 16 + lane] = s0;
  }
  LGKM0();
  SBAR();
  if (tid < 64) {
    float t4 = sm.u.pp.partial[0][tid] + sm.u.pp.partial[1][tid] +
               sm.u.pp.partial[2][tid] + sm.u.pp.partial[3][tid];
    sm.u.pp.rinv[tid] = 1.0f / t4;
  }
  LGKM0();
  SBAR();
  // preload every rinv value needed later (vt[1] staging will clobber the table)
  const bool wr8 = (wid < 8);                // attn-write role: 8 waves, 8 rows each
  const int wrow = wid * 8 + (lane >> 3);    // 0..63 (only meaningful for wr8)
  const float rvs = sm.u.pp.rinv[wrow & 63];
  float rv16[16];
  if (pkh == 0) {
    #pragma unroll
    for (int r = 0; r < 16; ++r) {
      const int rowreg = (r & 3) + 8 * (r >> 2) + 4 * l5;
      rv16[r] = sm.u.pp.rinv[prg * 32 + rowreg];
    }
  }
  LGKM0();                                   // all rinv reads done
  VMC(0);                                    // V0 landed
  SBAR();

  // ---------------- Phase 2: PV (32x32x16, pkh key-half split) + attn write ----------------
  f32x16 acc = {};
  const char* pArow = (const char*)sm.p + (prg * 32 + l31) * 2048;
  const int paswz = ((prg * 32 + l31) & 7) << 4;
  const char* wprow = (const char*)sm.p + wrow * 2048;
  const int wswz = (wrow & 7) << 4;
  float* wdst = gattn + ((size_t)bh * N_ + qt * 64 + wrow) * N_ + (lane & 7) * 4;
  const int dpv = pkg * 32 + l31;
  const int voff = (dpv * 64 + pkh * 32 + l5 * 16) ^ ((dpv & 7) << 4);

  #pragma unroll 2
  for (int kt = 0; kt < 32; ++kt) {
    if (kt < 31) issueV(kt + 1);
    const char* vbase = sm.u.vt[kt & 1];
    u16x8 vh = *(const u16x8*)(vbase + voff);
    u16x8 vl = *(const u16x8*)(vbase + 8192 + voff);
    u16x8 pa = *(const u16x8*)(pArow + ((kt * 64 + pkh * 32 + l5 * 16) ^ paswz));
    __builtin_amdgcn_s_setprio(1);
    acc = mfma32(pa, vh, acc);
    acc = mfma32(pa, vl, acc);
    __builtin_amdgcn_s_setprio(0);
    if (wr8) {                               // full-line attn write: 8 rows x 128B per wave
      u16x4 pw = *(const u16x4*)(wprow + ((kt * 64 + (lane & 7) * 8) ^ wswz));
      f32x4 o;
      o[0] = bf2f(pw[0]) * rvs; o[1] = bf2f(pw[1]) * rvs;
      o[2] = bf2f(pw[2]) * rvs; o[3] = bf2f(pw[3]) * rvs;
      __builtin_nontemporal_store(o, (f32x4*)(wdst + kt * 32));
    }
    LGKM0();
    if (kt < 31) {
      if (wr8) { VMC(1); }                   // leave the store in flight
      else     { VMC(0); }
    }
    SBAR();
  }

  // ---------------- O-combine across pkh halves ----------------
  {
    char* cbase = sm.u.comb[prg * 4 + pkg] + lane * 64;
    if (pkh == 1) {
      #pragma unroll
      for (int q = 0; q < 4; ++q) {
        f32x4 v = {acc[q * 4], acc[q * 4 + 1], acc[q * 4 + 2], acc[q * 4 + 3]};
        *(f32x4*)(cbase + q * 16) = v;
      }
    }
    LGKM0();
    SBAR();
    if (pkh == 0) {
      #pragma unroll
      for (int q = 0; q < 4; ++q) {
        f32x4 v = *(const f32x4*)(cbase + q * 16);
        acc[q * 4] += v[0]; acc[q * 4 + 1] += v[1];
        acc[q * 4 + 2] += v[2]; acc[q * 4 + 3] += v[3];
      }
      // epilogue: ao -> proj-image layout (bf16 hi/lo)
      const int col5 = hh * 4 + pkg;         // col>>5
      const int mt = bb * 8 + (qt >> 1);
      char* Tbase = aoimg + ((size_t)(mt * 32 + col5)) * 16384;
      const int klb = l31 * 2;
      #pragma unroll
      for (int r = 0; r < 16; ++r) {
        const int rowreg = (r & 3) + 8 * (r >> 2) + 4 * l5;
        const int rl = (qt & 1) * 64 + prg * 32 + rowreg;
        const int swz = (rl & 7) << 4;
        float val = acc[r] * rv16[r];
        unsigned short hv = f2bf(val);
        unsigned short lv = f2bf(val - bf2f(hv));
        char* rp = Tbase + rl * 128;
        __builtin_nontemporal_store(hv, (unsigned short*)(rp + (klb ^ swz)));
        __builtin_nontemporal_store(lv, (unsigned short*)(rp + ((64 + klb) ^ swz)));
      }
    }
  }
}

// ================= K2: out = ao @ W^T + b (128x128 tiles, 512 blocks) =================
struct K2Smem {
  char A[2][16384];
  char Bm[2][16384];
};

__global__ __launch_bounds__(512, 2)
void proj_kernel(const char* __restrict__ aoimg, const char* __restrict__ wimg,
                 const float* __restrict__ gbias, float* __restrict__ gout) {
  __shared__ K2Smem sm;
  const int nt = blockIdx.x & 7;             // nt = XCD (W slice L2-resident)
  const int mt = blockIdx.x >> 3;
  const int tid = threadIdx.x;
  const int wid = tid >> 6, lane = tid & 63;
  const int wr = wid >> 2, wc = wid & 3;     // wave: 64 rows x 32 cols
  const int l15 = lane & 15, l4 = lane >> 4;

  auto issue = [&](int s) {
    const char* sa = aoimg + ((size_t)(mt * 32 + s)) * 16384 + tid * 16;
    gl_lds16(sa, sm.A[s & 1] + (tid >> 6) * 1024);
    gl_lds16(sa + 8192, sm.A[s & 1] + 8192 + (tid >> 6) * 1024);
    const char* sb = wimg + ((size_t)(nt * 32 + s)) * 16384 + tid * 16;
    gl_lds16(sb, sm.Bm[s & 1] + (tid >> 6) * 1024);
    gl_lds16(sb + 8192, sm.Bm[s & 1] + 8192 + (tid >> 6) * 1024);
  };

  f32x4 acc[4][2];
  #pragma unroll
  for (int i = 0; i < 4; ++i)
    #pragma unroll
    for (int j = 0; j < 2; ++j) acc[i][j] = f32x4{0.f, 0.f, 0.f, 0.f};

  issue(0);
  VMC(0);
  SBAR();
  #pragma unroll 1
  for (int s = 0; s < 32; ++s) {
    if (s < 31) issue(s + 1);
    const char* Ab = sm.A[s & 1];
    const char* Bb = sm.Bm[s & 1];
    u16x8 ah[4], al[4], bh[2], bl[2];
    #pragma unroll
    for (int rt = 0; rt < 4; ++rt) {
      const int rl = wr * 64 + rt * 16 + l15;
      const char* rp = Ab + rl * 128;
      const int swz = (rl & 7) << 4;
      ah[rt] = *(const u16x8*)(rp + ((l4 * 16) ^ swz));
      al[rt] = *(const u16x8*)(rp + ((64 + l4 * 16) ^ swz));
    }
    #pragma unroll
    for (int ct = 0; ct < 2; ++ct) {
      const int cl = wc * 32 + ct * 16 + l15;
      const char* rp = Bb + cl * 128;
      const int swz = (cl & 7) << 4;
      bh[ct] = *(const u16x8*)(rp + ((l4 * 16) ^ swz));
      bl[ct] = *(const u16x8*)(rp + ((64 + l4 * 16) ^ swz));
    }
    __builtin_amdgcn_s_setprio(1);
    #pragma unroll
    for (int rt = 0; rt < 4; ++rt)
      #pragma unroll
      for (int ct = 0; ct < 2; ++ct)
        acc[rt][ct] = mfma16(ah[rt], bh[ct], acc[rt][ct]);
    #pragma unroll
    for (int rt = 0; rt < 4; ++rt)
      #pragma unroll
      for (int ct = 0; ct < 2; ++ct)
        acc[rt][ct] = mfma16(ah[rt], bl[ct], acc[rt][ct]);
    #pragma unroll
    for (int rt = 0; rt < 4; ++rt)
      #pragma unroll
      for (int ct = 0; ct < 2; ++ct)
        acc[rt][ct] = mfma16(al[rt], bh[ct], acc[rt][ct]);
    __builtin_amdgcn_s_setprio(0);
    LGKM0();
    if (s < 31) VMC(0);
    SBAR();
  }

  #pragma unroll
  for (int ct = 0; ct < 2; ++ct) {
    const int col = nt * 128 + wc * 32 + ct * 16 + l15;
    const float bv = gbias[col];
    #pragma unroll
    for (int rt = 0; rt < 4; ++rt) {
      float* dst = gout + (size_t)(mt * 128 + wr * 64 + rt * 16 + l4 * 4) * DIM_ + col;
      #pragma unroll
      for (int r = 0; r < 4; ++r)
        dst[(size_t)r * DIM_] = acc[rt][ct][r] + bv;
    }
  }
}

extern "C" void kernel_launch(void* const* d_in, const int* in_sizes, int n_in,
                              void* d_out, int out_size, void* d_ws, size_t ws_size,
                              hipStream_t stream) {
  const float* q    = (const float*)d_in[0];
  const float* k    = (const float*)d_in[1];
  const float* v    = (const float*)d_in[2];
  const float* W    = (const float*)d_in[3];
  const float* bias = (const float*)d_in[4];
  float* out  = (float*)d_out;
  float* attn = out + (size_t)B_ * N_ * DIM_;      // outputs: [out | attn]

  char* ws = (char*)d_ws;                          // needs 100 MB
  char* kimg  = ws + WS_KIMG;
  char* vimg  = ws + WS_VIMG;
  char* wimg  = ws + WS_WIMG;
  char* aoimg = ws + WS_AOIMG;

  prep_all<<<3584, 256, 0, stream>>>(k, v, W, kimg, vimg, wimg);
  attn_kernel<<<B_ * H_ * (N_ / 64), 1024, 0, stream>>>(q, kimg, vimg, attn, aoimg);
  proj_kernel<<<512, 512, 0, stream>>>(aoimg, wimg, bias, out);
}